// Round 4
// baseline (356.790 us; speedup 1.0000x reference)
//
#include <hip/hip_runtime.h>

// Problem constants (fixed by the reference file)
constexpr int cN1  = 100000;   // num_dst layer 1
constexpr int cN2  = 50000;    // num_dst layer 2
constexpr int cE0  = 1600000;
constexpr int cE1  = 800000;
constexpr int cIN  = 128;      // IN_F
constexpr int cH   = 256;      // H_F
constexpr int cCLS = 64;       // N_CLS

using bf16x8 = __attribute__((ext_vector_type(8))) short;   // 8 bf16 = 4 VGPRs
using f32x4  = __attribute__((ext_vector_type(4))) float;

__device__ __forceinline__ float bflo(unsigned int u) {
    union { unsigned int i; float f; } v; v.i = u << 16; return v.f;
}
__device__ __forceinline__ float bfhi(unsigned int u) {
    union { unsigned int i; float f; } v; v.i = u & 0xFFFF0000u; return v.f;
}
__device__ __forceinline__ unsigned int f2bf(float f) {   // RNE
    union { float f; unsigned int i; } v; v.f = f;
    return (v.i + 0x7FFFu + ((v.i >> 16) & 1u)) >> 16;
}

// -------- CSR row-start construction: dst is sorted, lower_bound per dst --------
__global__ void build_rows(const int* __restrict__ dst, int E, int num_dst,
                           int* __restrict__ row_start) {
    int d = blockIdx.x * blockDim.x + threadIdx.x;
    if (d > num_dst) return;
    int lo = 0, hi = E;
    while (lo < hi) {
        int mid = (lo + hi) >> 1;
        if (dst[mid] < d) lo = mid + 1; else hi = mid;
    }
    row_start[d] = lo;
}

// -------- fp32 -> bf16 bulk convert (8 elems/thread) --------
__global__ __launch_bounds__(256) void cvt_bf16(const float* __restrict__ in,
                                                unsigned short* __restrict__ out,
                                                int n8) {
    int i = blockIdx.x * 256 + threadIdx.x;
    if (i >= n8) return;
    const float4* p = (const float4*)in + (size_t)i * 2;
    float4 a = p[0], b = p[1];
    uint4 o;
    o.x = f2bf(a.x) | (f2bf(a.y) << 16);
    o.y = f2bf(a.z) | (f2bf(a.w) << 16);
    o.z = f2bf(b.x) | (f2bf(b.y) << 16);
    o.w = f2bf(b.z) | (f2bf(b.w) << 16);
    ((uint4*)out)[i] = o;
}

// -------- weight prep: bf16 + transpose, Wt[n][k] --------
__global__ void cvt_w(const float* __restrict__ Ws1, const float* __restrict__ Wn1,
                      const float* __restrict__ Wn2, const float* __restrict__ Ws2,
                      unsigned short* __restrict__ Wt1,
                      unsigned short* __restrict__ Wt2n,
                      unsigned short* __restrict__ Wt2s) {
    int i = blockIdx.x * 256 + threadIdx.x;
    if (i < 256 * 256) {
        int n = i / 256, k = i % 256;
        float v = (k < 128) ? Ws1[k * 256 + n] : Wn1[(k - 128) * 256 + n];
        Wt1[n * 256 + k] = (unsigned short)f2bf(v);
    } else if (i < 256 * 256 + 64 * 256) {
        int j = i - 65536; int n = j / 256, k = j % 256;
        Wt2n[n * 256 + k] = (unsigned short)f2bf(Wn2[k * 64 + n]);
    } else if (i < 256 * 256 + 2 * 64 * 256) {
        int j = i - 65536 - 16384; int n = j / 256, k = j % 256;
        Wt2s[n * 256 + k] = (unsigned short)f2bf(Ws2[k * 64 + n]);
    }
}

// -------- Wave-per-row gather + mean aggregation (bf16 rows, fp32 accum) --------
// One wave handles one dst row: 64 lanes = EPW edge slots x LPR row-chunk lanes.
// All lanes iterate the same edge list -> zero intra-wave divergence. Main loop
// keeps 2 independent 16B gathers in flight per lane; shfl_xor butterfly folds
// the edge slots at the end.
template<int K, bool ACCUM>
__global__ __launch_bounds__(256) void agg_wave(
        const unsigned short* __restrict__ src,
        const int* __restrict__ sidx,
        const int* __restrict__ rows,
        void* __restrict__ outv, int num_dst) {
    constexpr int LPR = K / 8;           // lanes per row: 16 (K=128) / 8 (K=64)
    constexpr int EPW = 64 / LPR;        // edge slots per wave: 4 / 8
    const int tid = threadIdx.x;
    const int lane = tid & 63;
    const int m = blockIdx.x * 4 + (tid >> 6);
    if (m >= num_dst) return;            // wave-uniform exit
    const int sub = lane / LPR;          // edge slot
    const int t   = lane % LPR;          // chunk within row

    const uint4* s4 = (const uint4*)src;
    const int e0 = rows[m], e1 = rows[m + 1];

    float acc[8];
    #pragma unroll
    for (int j = 0; j < 8; ++j) acc[j] = 0.f;

    auto addv = [&](uint4 v) {
        acc[0] += bflo(v.x); acc[1] += bfhi(v.x);
        acc[2] += bflo(v.y); acc[3] += bfhi(v.y);
        acc[4] += bflo(v.z); acc[5] += bfhi(v.z);
        acc[6] += bflo(v.w); acc[7] += bfhi(v.w);
    };

    int base = e0;
    for (; base + 2 * EPW <= e1; base += 2 * EPW) {
        const int sA = sidx[base + sub];
        const int sB = sidx[base + EPW + sub];
        uint4 vA = s4[(size_t)sA * LPR + t];
        uint4 vB = s4[(size_t)sB * LPR + t];
        addv(vA); addv(vB);
    }
    for (; base < e1; base += EPW) {
        const int idx = base + sub;
        if (idx < e1) {
            const int s = sidx[idx];
            addv(s4[(size_t)s * LPR + t]);
        }
    }

    // fold edge slots: butterfly over the sub dimension
    #pragma unroll
    for (int j = 0; j < 8; ++j) {
        #pragma unroll
        for (int off = LPR; off < 64; off <<= 1)
            acc[j] += __shfl_xor(acc[j], off, 64);
    }

    if (sub == 0) {
        const int deg = e1 - e0;
        const float inv = 1.0f / (float)(deg > 1 ? deg : 1);
        if (!ACCUM) {
            uint4 o;
            o.x = f2bf(acc[0] * inv) | (f2bf(acc[1] * inv) << 16);
            o.y = f2bf(acc[2] * inv) | (f2bf(acc[3] * inv) << 16);
            o.z = f2bf(acc[4] * inv) | (f2bf(acc[5] * inv) << 16);
            o.w = f2bf(acc[6] * inv) | (f2bf(acc[7] * inv) << 16);
            ((uint4*)outv)[(size_t)m * LPR + t] = o;
        } else {
            float* op = (float*)outv + (size_t)m * K + t * 8;
            float4 o0 = *(float4*)op, o1 = *(float4*)(op + 4);
            o0.x += acc[0] * inv; o0.y += acc[1] * inv;
            o0.z += acc[2] * inv; o0.w += acc[3] * inv;
            o1.x += acc[4] * inv; o1.y += acc[5] * inv;
            o1.z += acc[6] * inv; o1.w += acc[7] * inv;
            *(float4*)op = o0; *(float4*)(op + 4) = o1;
        }
    }
}

// -------- bf16 MFMA GEMM: C = [A1|A2] @ Bt^T (+bias)(+relu) --------
// A1/A2: [M][K1], [M][K2] bf16 row-major (K-concat). Bt: [N][K] bf16 (W^T).
// 256 threads = 4 waves in 2x2; wave tile = (WM*16) x (WN*16); BK=32.
// mfma_f32_16x16x32_bf16: A[m=lane&15][k=(lane>>4)*8+j], B[k][n=lane&15],
// D col=lane&15, row=(lane>>4)*4+reg  (guide-verified mappings).
template<int BM, int BN, int WM, int WN, bool RELU, bool HASBIAS, bool OUTBF16>
__global__ __launch_bounds__(256) void gemm_mfma(
        const unsigned short* __restrict__ A1, int K1,
        const unsigned short* __restrict__ A2, int K2,
        const unsigned short* __restrict__ Bt,
        const float* __restrict__ bias,
        void* __restrict__ Cout, int M, int N) {
    static_assert(2 * WM * 16 == BM && 2 * WN * 16 == BN, "wave tiling");
    __shared__ unsigned short As[BM][40];   // 32 + 8 pad
    __shared__ unsigned short Bs[BN][40];

    const int tid = threadIdx.x;
    const int m0 = blockIdx.x * BM, n0 = blockIdx.y * BN;
    const int lane = tid & 63, wave = tid >> 6;
    const int wrow = wave >> 1, wcol = wave & 1;
    const int quad = lane >> 4, l16 = lane & 15;
    const int K = K1 + K2;

    f32x4 acc[WM][WN];
    #pragma unroll
    for (int i = 0; i < WM; ++i)
        #pragma unroll
        for (int j = 0; j < WN; ++j)
            acc[i][j] = (f32x4){0.f, 0.f, 0.f, 0.f};

    for (int kb = 0; kb < K; kb += 32) {
        const unsigned short* Ab; int lda, kloc;
        if (kb < K1) { Ab = A1; lda = K1; kloc = kb; }
        else         { Ab = A2; lda = K2; kloc = kb - K1; }

        #pragma unroll
        for (int f = 0; f < (BM * 4) / 256; ++f) {
            int idx = tid + f * 256;
            int row = idx >> 2, q = idx & 3;
            int gm = m0 + row;
            uint4 v = make_uint4(0, 0, 0, 0);
            if (gm < M) v = *(const uint4*)(Ab + (size_t)gm * lda + kloc + q * 8);
            *(uint4*)&As[row][q * 8] = v;
        }
        #pragma unroll
        for (int f = 0; f < (BN * 4) / 256; ++f) {
            int idx = tid + f * 256;
            int row = idx >> 2, q = idx & 3;
            uint4 v = *(const uint4*)(Bt + (size_t)(n0 + row) * K + kb + q * 8);
            *(uint4*)&Bs[row][q * 8] = v;
        }
        __syncthreads();

        bf16x8 a[WM], b[WN];
        #pragma unroll
        for (int i = 0; i < WM; ++i)
            a[i] = *(const bf16x8*)&As[(wrow * WM + i) * 16 + l16][quad * 8];
        #pragma unroll
        for (int j = 0; j < WN; ++j)
            b[j] = *(const bf16x8*)&Bs[(wcol * WN + j) * 16 + l16][quad * 8];
        #pragma unroll
        for (int i = 0; i < WM; ++i)
            #pragma unroll
            for (int j = 0; j < WN; ++j)
                acc[i][j] = __builtin_amdgcn_mfma_f32_16x16x32_bf16(
                    a[i], b[j], acc[i][j], 0, 0, 0);
        __syncthreads();
    }

    // epilogue
    float bv[WN];
    #pragma unroll
    for (int j = 0; j < WN; ++j)
        bv[j] = HASBIAS ? bias[n0 + (wcol * WN + j) * 16 + l16] : 0.f;
    #pragma unroll
    for (int i = 0; i < WM; ++i) {
        #pragma unroll
        for (int r = 0; r < 4; ++r) {
            int gm = m0 + (wrow * WM + i) * 16 + quad * 4 + r;
            if (gm >= M) continue;
            #pragma unroll
            for (int j = 0; j < WN; ++j) {
                int gn = n0 + (wcol * WN + j) * 16 + l16;
                float v = acc[i][j][r] + bv[j];
                if (RELU) v = fmaxf(v, 0.f);
                if (OUTBF16)
                    ((unsigned short*)Cout)[(size_t)gm * N + gn] = (unsigned short)f2bf(v);
                else
                    ((float*)Cout)[(size_t)gm * N + gn] = v;
            }
        }
    }
}

extern "C" void kernel_launch(void* const* d_in, const int* in_sizes, int n_in,
                              void* d_out, int out_size, void* d_ws, size_t ws_size,
                              hipStream_t stream) {
    const float* x      = (const float*)d_in[0];
    const int*   src0   = (const int*)d_in[1];
    const int*   dst0   = (const int*)d_in[2];
    const int*   src1   = (const int*)d_in[3];
    const int*   dst1   = (const int*)d_in[4];
    const float* Wself1  = (const float*)d_in[7];
    const float* Wneigh1 = (const float*)d_in[8];
    const float* b1      = (const float*)d_in[9];
    const float* Wself2  = (const float*)d_in[10];
    const float* Wneigh2 = (const float*)d_in[11];
    const float* b2      = (const float*)d_in[12];
    float* out = (float*)d_out;

    // ---- workspace layout ----
    char* ws = (char*)d_ws;
    int* row0 = (int*)ws;                         // cN1+1
    int* row1 = row0 + (cN1 + 1);                 // cN2+1
    size_t off = (size_t)((cN1 + 1) + (cN2 + 1)) * sizeof(int);
    off = (off + 1023) & ~(size_t)1023;
    unsigned short* xb  = (unsigned short*)(ws + off);  off += (size_t)200000 * cIN * 2;
    unsigned short* nb  = (unsigned short*)(ws + off);  off += (size_t)cN1 * cIN * 2;
    unsigned short* h1b = (unsigned short*)(ws + off);  off += (size_t)cN1 * cH * 2;
    unsigned short* zb  = (unsigned short*)(ws + off);  off += (size_t)cN1 * cCLS * 2;
    unsigned short* Wt1  = (unsigned short*)(ws + off); off += 256 * 256 * 2;
    unsigned short* Wt2n = (unsigned short*)(ws + off); off += 64 * 256 * 2;
    unsigned short* Wt2s = (unsigned short*)(ws + off); off += 64 * 256 * 2;

    // CSR row offsets
    build_rows<<<(cN1 + 1 + 255) / 256, 256, 0, stream>>>(dst0, cE0, cN1, row0);
    build_rows<<<(cN2 + 1 + 255) / 256, 256, 0, stream>>>(dst1, cE1, cN2, row1);

    // dtype prep
    cvt_bf16<<<(200000 * cIN / 8 + 255) / 256, 256, 0, stream>>>(x, xb, 200000 * cIN / 8);
    cvt_w<<<(256 * 256 + 2 * 64 * 256 + 255) / 256, 256, 0, stream>>>(
        Wself1, Wneigh1, Wneigh2, Wself2, Wt1, Wt2n, Wt2s);

    // Layer 1: nb = segmean(xb); h1b = relu([xb|nb] @ Wt1^T + b1)
    agg_wave<cIN, false><<<(cN1 + 3) / 4, 256, 0, stream>>>(
        xb, src0, row0, nb, cN1);
    gemm_mfma<128, 128, 4, 4, true, true, true>
        <<<dim3((cN1 + 127) / 128, cH / 128), 256, 0, stream>>>(
        xb, cIN, nb, cIN, Wt1, b1, h1b, cN1, cH);

    // Layer 2 (transform-then-aggregate): zb = h1b @ Wn2; out = h1b[:50k]@Ws2+b2;
    // out += segmean(zb)
    gemm_mfma<128, 64, 4, 2, false, false, true>
        <<<dim3((cN1 + 127) / 128, 1), 256, 0, stream>>>(
        h1b, cH, nullptr, 0, Wt2n, nullptr, zb, cN1, cCLS);
    gemm_mfma<128, 64, 4, 2, false, true, false>
        <<<dim3((cN2 + 127) / 128, 1), 256, 0, stream>>>(
        h1b, cH, nullptr, 0, Wt2s, b2, out, cN2, cCLS);
    agg_wave<cCLS, true><<<(cN2 + 3) / 4, 256, 0, stream>>>(
        zb, src1, row1, out, cN2);
}